// Round 3
// baseline (86.042 us; speedup 1.0000x reference)
//
#include <hip/hip_runtime.h>
#include <hip/hip_bf16.h>
#include <stdint.h>

#define NB 64
#define N_IN 195
#define N_OUT 778
#define D_IN 256
#define D_OUTC 128
#define NS 9
#define KTOT 2304      // NS * D_IN
#define MM 49792       // NB * N_OUT
#define BM 64
#define BK 64
#define NWG (MM / BM)          // 778
#define POOL_BLOCKS (MM / 2)   // 24896
#define WT_BLOCKS ((D_OUTC * KTOT) / 256)  // 1152

using short8 = __attribute__((ext_vector_type(8))) short;
using f32x4  = __attribute__((ext_vector_type(4))) float;

__device__ __forceinline__ void gload16(const void* g, void* l) {
  __builtin_amdgcn_global_load_lds(
      (const __attribute__((address_space(1))) uint32_t*)g,
      (__attribute__((address_space(3))) uint32_t*)l, 16, 0, 0);
}

// ---------------- kernel 1: pool + bf16 convert, fused W-transpose ----------
__global__ __launch_bounds__(256) void prep_kernel(
    const float* __restrict__ x, const int* __restrict__ col,
    const float* __restrict__ value, const float* __restrict__ W,
    __hip_bfloat16* __restrict__ pooled, __hip_bfloat16* __restrict__ Wt) {
  int bid = blockIdx.x;
  if (bid < POOL_BLOCKS) {
    int m = bid * 2 + (threadIdx.x >> 7);
    int t = threadIdx.x & 127;
    int b = (unsigned)m / N_OUT;
    int n = m - b * N_OUT;
    int j = 3 * n;
    int c0 = col[j], c1 = col[j + 1], c2 = col[j + 2];
    float v0 = value[j], v1 = value[j + 1], v2 = value[j + 2];
    const float2* x0 = (const float2*)(x + ((size_t)b * N_IN + c0) * D_IN);
    const float2* x1 = (const float2*)(x + ((size_t)b * N_IN + c1) * D_IN);
    const float2* x2 = (const float2*)(x + ((size_t)b * N_IN + c2) * D_IN);
    float2 a0 = x0[t], a1 = x1[t], a2 = x2[t];
    float r0 = v0 * a0.x + v1 * a1.x + v2 * a2.x;
    float r1 = v0 * a0.y + v1 * a1.y + v2 * a2.y;
    __hip_bfloat162 pk;
    pk.x = __float2bfloat16(r0);
    pk.y = __float2bfloat16(r1);
    ((__hip_bfloat162*)(pooled + (size_t)m * D_IN))[t] = pk;
  } else {
    int idx = (bid - POOL_BLOCKS) * 256 + threadIdx.x;  // over 128*2304
    int o = idx / KTOT, k = idx - o * KTOT;
    Wt[idx] = __float2bfloat16(W[(size_t)k * D_OUTC + o]);
  }
}

// ---------------- kernel 2: gather-GEMM, BM=64 for 3-blocks/CU TLP ----------
// out tile 64x128 per block; 4 waves, each 32x64.
__global__ __launch_bounds__(256) void gemm_kernel(
    const __hip_bfloat16* __restrict__ pooled,
    const __hip_bfloat16* __restrict__ Wt,
    const int* __restrict__ indices,
    const float* __restrict__ bias,
    float* __restrict__ out) {
  __shared__ __hip_bfloat16 Asm[2][BM * BK];      // 2 x 8 KB, swizzled rows
  __shared__ __hip_bfloat16 Bsm[2][D_OUTC * BK];  // 2 x 16 KB

  const int tid  = threadIdx.x;
  const int wave = tid >> 6;
  const int lane = tid & 63;
  const int wr = wave >> 1, wc = wave & 1;     // wave tile 32x64
  const int srow = lane >> 3, schunk = lane & 7;

  // XCD-aware bijective block swizzle (m204 variant; NWG=778, 778%8=2)
  const int bidr = blockIdx.x;
  const int xcd = bidr & 7, loc = bidr >> 3;
  const int q8 = NWG >> 3, r8 = NWG & 7;       // 97, 2
  const int wg = (xcd < r8 ? xcd * (q8 + 1) : r8 * (q8 + 1) + (xcd - r8) * q8) + loc;
  const int bm = wg * BM;

  // A staging precompute: 2 instrs/wave, 8 rows each (row = 128B)
  int n_i[2], b778_i[2], ax_i[2];
  #pragma unroll
  for (int i = 0; i < 2; ++i) {
    int r = wave * 16 + i * 8 + srow;          // tile row 0..63
    int m = bm + r;
    int b = (unsigned)m / N_OUT;
    int n = m - b * N_OUT;
    n_i[i] = n;
    b778_i[i] = b * N_OUT;
    ax_i[i] = (schunk ^ (r & 7)) * 8;          // source-permuted chunk (elems)
  }
  // B staging precompute: 4 instrs/wave
  const __hip_bfloat16* wtb_i[4];
  #pragma unroll
  for (int i = 0; i < 4; ++i) {
    int o = wave * 32 + i * 8 + srow;          // Wt row 0..127
    wtb_i[i] = Wt + (size_t)o * KTOT + (size_t)((schunk ^ (o & 7)) * 8);
  }

  f32x4 acc[2][4];
  #pragma unroll
  for (int i = 0; i < 2; ++i)
    #pragma unroll
    for (int j = 0; j < 4; ++j)
      acc[i][j] = f32x4{0.f, 0.f, 0.f, 0.f};

  char* AsmB = (char*)&Asm[0][0];
  char* BsmB = (char*)&Bsm[0][0];

  // stage one (s0, d0) phase into buffer `buf`
  auto stage = [&](int buf, int d0, int k0, const int* gi) {
    #pragma unroll
    for (int i = 0; i < 2; ++i) {
      const __hip_bfloat16* srcA =
          pooled + ((size_t)(b778_i[i] + gi[i]) * D_IN + d0 + ax_i[i]);
      gload16(srcA, AsmB + buf * 8192 + (wave * 2 + i) * 1024);
    }
    #pragma unroll
    for (int i = 0; i < 4; ++i) {
      const __hip_bfloat16* srcB = wtb_i[i] + k0;
      gload16(srcB, BsmB + buf * 16384 + (wave * 4 + i) * 1024);
    }
  };

  auto compute = [&](int buf) {
    const char* Ab = AsmB + buf * 8192;
    const char* Bb = BsmB + buf * 16384;
    #pragma unroll
    for (int h = 0; h < 2; ++h) {
      short8 af[2], bf[4];
      const int cb = h * 64 + (lane >> 4) * 16;   // byte col within row
      #pragma unroll
      for (int i = 0; i < 2; ++i) {
        int r = wr * 32 + i * 16 + (lane & 15);
        af[i] = *(const short8*)(Ab + r * 128 + (cb ^ ((r & 7) << 4)));
      }
      #pragma unroll
      for (int j = 0; j < 4; ++j) {
        int o = wc * 64 + j * 16 + (lane & 15);
        bf[j] = *(const short8*)(Bb + o * 128 + (cb ^ ((o & 7) << 4)));
      }
      #pragma unroll
      for (int i = 0; i < 2; ++i)
        #pragma unroll
        for (int j = 0; j < 4; ++j)
          acc[i][j] = __builtin_amdgcn_mfma_f32_16x16x32_bf16(
              af[i], bf[j], acc[i][j], 0, 0, 0);
    }
  };

  // ---- software pipeline over 36 phases (9 spirals x 4 quarters) ----------
  int giA[2], giB[2];
  #pragma unroll
  for (int i = 0; i < 2; ++i) giA[i] = indices[n_i[i] * NS + 0];
  stage(0, 0, 0, giA);
  __syncthreads();

  for (int s0 = 0; s0 < NS; ++s0) {
    if (s0 < NS - 1) {
      #pragma unroll
      for (int i = 0; i < 2; ++i) giB[i] = indices[n_i[i] * NS + s0 + 1];
    }
    #pragma unroll
    for (int q = 0; q < 4; ++q) {
      // prefetch next phase into the other buffer
      if (q < 3) {
        stage((q & 1) ^ 1, (q + 1) * 64, s0 * 256 + (q + 1) * 64, giA);
      } else if (s0 < NS - 1) {
        stage((q & 1) ^ 1, 0, (s0 + 1) * 256, giB);
      }
      compute(q & 1);
      __syncthreads();   // drains vmcnt(0); TLP (3 blocks/CU) hides the stall
    }
    if (s0 < NS - 1) {
      #pragma unroll
      for (int i = 0; i < 2; ++i) giA[i] = giB[i];
    }
  }

  // ---- epilogue: bias + relu, fp32 stores
  #pragma unroll
  for (int j = 0; j < 4; ++j) {
    int colo = wc * 64 + j * 16 + (lane & 15);
    float bo = bias[colo];
    #pragma unroll
    for (int i = 0; i < 2; ++i) {
      #pragma unroll
      for (int qq = 0; qq < 4; ++qq) {
        int row = bm + wr * 32 + i * 16 + (lane >> 4) * 4 + qq;
        float v = acc[i][j][qq] + bo;
        out[(size_t)row * D_OUTC + colo] = fmaxf(v, 0.f);
      }
    }
  }
}

extern "C" void kernel_launch(void* const* d_in, const int* in_sizes, int n_in,
                              void* d_out, int out_size, void* d_ws, size_t ws_size,
                              hipStream_t stream) {
  const float* x       = (const float*)d_in[0];
  // d_in[1] = row (unused: structure is repeat(arange(N_out),3))
  const int*   col     = (const int*)d_in[2];
  const float* value   = (const float*)d_in[3];
  const int*   indices = (const int*)d_in[4];
  const float* W       = (const float*)d_in[5];
  const float* bias    = (const float*)d_in[6];
  float* out           = (float*)d_out;

  __hip_bfloat16* pooled = (__hip_bfloat16*)d_ws;
  __hip_bfloat16* Wt = (__hip_bfloat16*)((char*)d_ws + (size_t)MM * D_IN * 2);

  prep_kernel<<<POOL_BLOCKS + WT_BLOCKS, 256, 0, stream>>>(x, col, value, W,
                                                           pooled, Wt);
  gemm_kernel<<<NWG, 256, 0, stream>>>(pooled, Wt, indices, bias, out);
}

// Round 4
// 74.339 us; speedup vs baseline: 1.1574x; 1.1574x over previous
//
#include <hip/hip_runtime.h>
#include <hip/hip_bf16.h>
#include <stdint.h>

#define N_IN 195
#define N_OUT 778
#define D_IN 256
#define D_OUTC 128
#define NS 9
#define KTOT 2304          // NS * D_IN
#define MM 49792           // 64 * 778
#define BM 256
#define NPH 36             // 9 spirals x 4 quarters (BK=64)
#define NWG 195            // ceil(MM / BM)
#define POOL_BLOCKS 12448  // MM / 4
#define WT_BLOCKS 1152     // 128*2304/256

using short8 = __attribute__((ext_vector_type(8))) short;
using short4v = __attribute__((ext_vector_type(4))) short;
using f32x4  = __attribute__((ext_vector_type(4))) float;

__device__ __forceinline__ void gload16(const void* g, void* l) {
  __builtin_amdgcn_global_load_lds(
      (const __attribute__((address_space(1))) uint32_t*)g,
      (__attribute__((address_space(3))) uint32_t*)l, 16, 0, 0);
}

__device__ __forceinline__ unsigned short f2bf(float f) {  // RNE, same as __float2bfloat16
  uint32_t u = __float_as_uint(f);
  return (unsigned short)((u + 0x7FFFu + ((u >> 16) & 1u)) >> 16);
}

// ---------------- kernel 1: pool + bf16 convert, fused W-transpose ----------
__global__ __launch_bounds__(256) void prep_kernel(
    const float* __restrict__ x, const int* __restrict__ col,
    const float* __restrict__ value, const float* __restrict__ W,
    unsigned short* __restrict__ pooled, unsigned short* __restrict__ Wt) {
  int bid = blockIdx.x;
  if (bid < POOL_BLOCKS) {
    int m = bid * 4 + (threadIdx.x >> 6);
    int lane = threadIdx.x & 63;
    int b = (unsigned)m / N_OUT;
    int n = m - b * N_OUT;
    int j = 3 * n;
    int c0 = col[j], c1 = col[j + 1], c2 = col[j + 2];
    float v0 = value[j], v1 = value[j + 1], v2 = value[j + 2];
    const float4* x0 = (const float4*)(x + ((size_t)b * N_IN + c0) * D_IN);
    const float4* x1 = (const float4*)(x + ((size_t)b * N_IN + c1) * D_IN);
    const float4* x2 = (const float4*)(x + ((size_t)b * N_IN + c2) * D_IN);
    float4 a0 = x0[lane], a1 = x1[lane], a2 = x2[lane];
    short4v pk;
    pk[0] = (short)f2bf(v0 * a0.x + v1 * a1.x + v2 * a2.x);
    pk[1] = (short)f2bf(v0 * a0.y + v1 * a1.y + v2 * a2.y);
    pk[2] = (short)f2bf(v0 * a0.z + v1 * a1.z + v2 * a2.z);
    pk[3] = (short)f2bf(v0 * a0.w + v1 * a1.w + v2 * a2.w);
    ((short4v*)(pooled + (size_t)m * D_IN))[lane] = pk;
  } else {
    int idx = (bid - POOL_BLOCKS) * 256 + threadIdx.x;  // over 128*2304
    int o = idx / KTOT, k = idx - o * KTOT;
    Wt[idx] = f2bf(W[(size_t)k * D_OUTC + o]);
  }
}

// ---------------- kernel 2: gather-GEMM --------------------------------------
// 512 thr = 8 waves, wave tile 32 rows x 128 cols. A gathered direct-to-reg,
// B via LDS (4 buffers x 16KB), counted-vmcnt pipeline, raw barriers.
__global__ __launch_bounds__(512) void gemm_kernel(
    const unsigned short* __restrict__ pooled,   // bf16 bits [MM][256]
    const unsigned short* __restrict__ Wt,       // bf16 bits [128][2304]
    const int* __restrict__ indices,
    const float* __restrict__ bias,
    float* __restrict__ out) {
  __shared__ unsigned short Bsm[4][64 * 128];    // 4 x 16 KB = 64 KB

  const int tid = threadIdx.x;
  const int wave = tid >> 6, lane = tid & 63;

  // XCD-aware bijective swizzle (NWG=195: q8=24, r8=3)
  const int xcd = blockIdx.x & 7, loc = blockIdx.x >> 3;
  const int q8 = NWG >> 3, r8 = NWG & 7;
  const int wg = (xcd < r8 ? xcd * (q8 + 1) : r8 * (q8 + 1) + (xcd - r8) * q8) + loc;
  const int bm = wg * BM;

  // per-lane A meta (2 m-frags of 16 rows; lane&15 selects row in frag)
  int nn0, nn1; size_t gb0, gb1;
  {
    int m0 = bm + wave * 32 + (lane & 15);        if (m0 >= MM) m0 = MM - 1;
    int m1 = bm + wave * 32 + 16 + (lane & 15);   if (m1 >= MM) m1 = MM - 1;
    int b0 = (unsigned)m0 / N_OUT, b1 = (unsigned)m1 / N_OUT;
    nn0 = m0 - b0 * N_OUT; nn1 = m1 - b1 * N_OUT;
    gb0 = (size_t)b0 * N_OUT; gb1 = (size_t)b1 * N_OUT;
  }
  const int kk = (lane >> 4) * 8;   // k-offset (elems) within 32-slice

  // B staging meta: 2 gload16/thread/phase; o = j*64 + (tid>>3)
  const int so = tid >> 3;
  const int sc = (tid & 7) ^ (so & 7);           // XOR-swizzled chunk
  const unsigned short* wt0 = Wt + (size_t)so * KTOT + sc * 8;
  const unsigned short* wt1 = Wt + (size_t)(64 + so) * KTOT + sc * 8;
  char* BsmB = (char*)&Bsm[0][0];

  // gather indices: current + one-spiral prefetch
  int gu0 = indices[nn0 * NS + 0], gu1 = indices[nn1 * NS + 0];
  int gp0 = indices[nn0 * NS + 1], gp1 = indices[nn1 * NS + 1];

  f32x4 acc[2][8];
  #pragma unroll
  for (int i = 0; i < 2; ++i)
    #pragma unroll
    for (int n = 0; n < 8; ++n) acc[i][n] = f32x4{0.f, 0.f, 0.f, 0.f};

  short8 afA[2][2], afB[2][2];

  auto stageB = [&](int p) {
    int k0 = (p >> 2) * 256 + (p & 3) * 64;
    gload16(wt0 + k0, BsmB + (p & 3) * 16384 + tid * 16);
    gload16(wt1 + k0, BsmB + (p & 3) * 16384 + 8192 + tid * 16);
  };

  auto loadA = [&](short8 af[2][2], int p, int g0, int g1) {
    const int d0 = (p & 3) * 64 + kk;
    const unsigned short* a0 = pooled + (((gb0 + (size_t)g0) << 8) + d0);
    const unsigned short* a1 = pooled + (((gb1 + (size_t)g1) << 8) + d0);
    af[0][0] = *(const short8*)(a0);
    af[0][1] = *(const short8*)(a0 + 32);
    af[1][0] = *(const short8*)(a1);
    af[1][1] = *(const short8*)(a1 + 32);
  };

  auto compute = [&](const short8 af[2][2], int p) {
    const char* Bb = BsmB + (p & 3) * 16384;
    #pragma unroll
    for (int h = 0; h < 2; ++h) {
      short8 bf[8];
      const int cb = h * 64 + (lane >> 4) * 16;
      #pragma unroll
      for (int n = 0; n < 8; ++n) {
        int o = n * 16 + (lane & 15);
        bf[n] = *(const short8*)(Bb + o * 128 + (cb ^ ((o & 7) << 4)));
      }
      #pragma unroll
      for (int n = 0; n < 8; ++n) {
        acc[0][n] = __builtin_amdgcn_mfma_f32_16x16x32_bf16(af[0][h], bf[n], acc[0][n], 0, 0, 0);
        acc[1][n] = __builtin_amdgcn_mfma_f32_16x16x32_bf16(af[1][h], bf[n], acc[1][n], 0, 0, 0);
      }
    }
  };

  // gi rotate (spiral boundary) for the phase about to be loaded (p+1)
  auto rotate = [&](int p) {
    if (((p + 1) & 3) == 0) {
      gu0 = gp0; gu1 = gp1;
      int sp = ((p + 1) >> 2) + 1;
      if (sp < NS) { gp0 = indices[nn0 * NS + sp]; gp1 = indices[nn1 * NS + sp]; }
    }
  };

  // ---- prologue: phases 0,1 staged; A(0) in flight -------------------------
  stageB(0);
  asm volatile("" ::: "memory");   // pin stage(0) oldest
  stageB(1);
  loadA(afA, 0, gu0, gu1);

  // ---- main loop p = 0..33 (two phases per iteration, static reg parity) ---
#define BODY(P, CUR, NXT, CNT)                                   \
  {                                                              \
    stageB((P) + 2);                                             \
    rotate(P);                                                   \
    loadA(NXT, (P) + 1, gu0, gu1);                               \
    asm volatile("s_waitcnt vmcnt(" #CNT ")" ::: "memory");      \
    __builtin_amdgcn_s_barrier();                                \
    asm volatile("" ::: "memory");                               \
    compute(CUR, P);                                             \
  }

  for (int pp = 0; pp < 17; ++pp) {
    int p = 2 * pp;
    BODY(p,     afA, afB, 12)
    BODY(p + 1, afB, afA, 12)
  }
  // ---- peel p = 34, 35 ------------------------------------------------------
  {
    loadA(afB, 35, gu0, gu1);
    asm volatile("s_waitcnt vmcnt(10)" ::: "memory");
    __builtin_amdgcn_s_barrier();
    asm volatile("" ::: "memory");
    compute(afA, 34);
  }
  {
    asm volatile("s_waitcnt vmcnt(4)" ::: "memory");
    __builtin_amdgcn_s_barrier();
    asm volatile("" ::: "memory");
    compute(afB, 35);
  }
#undef BODY

  // ---- epilogue: bias + relu ------------------------------------------------
  #pragma unroll
  for (int n = 0; n < 8; ++n) {
    int colo = n * 16 + (lane & 15);
    float bo = bias[colo];
    #pragma unroll
    for (int i = 0; i < 2; ++i) {
      int rb = bm + wave * 32 + i * 16 + (lane >> 4) * 4;
      #pragma unroll
      for (int q = 0; q < 4; ++q) {
        int row = rb + q;
        if (row < MM) out[(size_t)row * D_OUTC + colo] = fmaxf(acc[i][n][q] + bo, 0.f);
      }
    }
  }
}

extern "C" void kernel_launch(void* const* d_in, const int* in_sizes, int n_in,
                              void* d_out, int out_size, void* d_ws, size_t ws_size,
                              hipStream_t stream) {
  const float* x       = (const float*)d_in[0];
  // d_in[1] = row (unused: structure is repeat(arange(N_out),3))
  const int*   col     = (const int*)d_in[2];
  const float* value   = (const float*)d_in[3];
  const int*   indices = (const int*)d_in[4];
  const float* W       = (const float*)d_in[5];
  const float* bias    = (const float*)d_in[6];
  float* out           = (float*)d_out;

  unsigned short* pooled = (unsigned short*)d_ws;
  unsigned short* Wt = (unsigned short*)((char*)d_ws + (size_t)MM * D_IN * 2);

  prep_kernel<<<POOL_BLOCKS + WT_BLOCKS, 256, 0, stream>>>(x, col, value, W,
                                                           pooled, Wt);
  gemm_kernel<<<NWG, 512, 0, stream>>>(pooled, Wt, indices, bias, out);
}